// Round 9
// baseline (60.721 us; speedup 1.0000x reference)
//
#include <hip/hip_runtime.h>

// Problem constants: B=8, N=2048, M=2048, D=128
#define B_DIM 8
#define N_DIM 2048
#define M_DIM 2048
#define D_DIM 128
#define NT_TILES 4

typedef __bf16 bf16_t;
typedef bf16_t bf16x8 __attribute__((ext_vector_type(8)));
typedef float f32x4 __attribute__((ext_vector_type(4)));

// lgkm-only barrier: never drains vmcnt, so global stores (and prefetch
// loads) stay in flight across tile boundaries.
__device__ __forceinline__ void lgkm_barrier() {
    asm volatile("s_waitcnt lgkmcnt(0)" ::: "memory");
    __builtin_amdgcn_s_barrier();
}

// ---------------------------------------------------------------------------
// Fused kernel, R6 structure + epilogue LDS-transpose for contiguous stores.
//
// Per block: stage A panel (bf16, fragmented+swizzled) + B tile 0; loop over
// 4 bx tiles: MFMA -> prefetch next B (f32->regs, issued BEFORE stores so
// later conversion waits are counted vmcnt) -> epilogue math in MFMA layout
// -> write finished tile to 64KB LDS Obuf (aliases dead Als+Bls) -> barrier
// -> read back row-major and store 512B-contiguous row segments (2 rows x
// 512B per wave instr = full 128B lines, halving TCC write requests vs the
// old 16x64B scatter) -> restage B from prefetched regs.
//
// LDS swizzles (all at the b128 bank floor):
//   bf16 staging granule: gran*16 + (r ^ gran)
//   Obuf f32x4 granule:   row*32 + (g ^ (row & 7))
// MFMA operands SWAPPED (mfma(B,A)): out-row = lane&15, out-col =
// (lane>>4)*4 + reg.
// ---------------------------------------------------------------------------
__global__ __launch_bounds__(256, 2) void fused_dist_kernel(
    const float* __restrict__ L, const float* __restrict__ R,
    float* __restrict__ out)
{
    __shared__ f32x4 ldsq[4096];              // 64 KB, aliased below
    bf16x8* Als = (bf16x8*)ldsq;              // [0, 32KB)
    bf16x8* Bls = (bf16x8*)(ldsq + 2048);     // [32KB, 64KB)
    __shared__ float nAs[128];
    __shared__ float nBs[128];

    const int tid  = threadIdx.x;
    const int bxg  = blockIdx.x;   // covers NT_TILES bx tiles
    const int by   = blockIdx.y;
    const int bz   = blockIdx.z;
    const int wid  = tid >> 6;
    const int lane = tid & 63;
    const int lr   = lane & 15;
    const int h    = lane >> 4;    // 0..3
    const int r    = tid >> 4;     // staging: row within 16-row group
    const int gran = tid & 15;     // staging: 8-elem chunk

    const float* Asrc = L + ((size_t)bz * N_DIM + (size_t)by * 128) * D_DIM;
    const float* Rbat = R + (size_t)bz * M_DIM * D_DIM;

    // ---- initial stage: A panel (bf16 RNE + norms from SAME rounded values)
    #pragma unroll
    for (int i = 0; i < 8; ++i) {
        int row = i * 16 + r;
        float4 v0 = ((const float4*)Asrc)[(size_t)row * 32 + gran * 2];
        float4 v1 = ((const float4*)Asrc)[(size_t)row * 32 + gran * 2 + 1];
        bf16x8 p = { (bf16_t)v0.x, (bf16_t)v0.y, (bf16_t)v0.z, (bf16_t)v0.w,
                     (bf16_t)v1.x, (bf16_t)v1.y, (bf16_t)v1.z, (bf16_t)v1.w };
        Als[i * 256 + gran * 16 + (r ^ gran)] = p;
        float s = 0.0f;
        #pragma unroll
        for (int j = 0; j < 8; ++j) { float x = (float)p[j]; s = fmaf(x, x, s); }
        s += __shfl_xor(s, 1); s += __shfl_xor(s, 2);
        s += __shfl_xor(s, 4); s += __shfl_xor(s, 8);
        if (gran == 0) nAs[i * 16 + r] = s;
    }
    // ---- initial stage: B tile 0
    {
        const float* Bsrc = Rbat + (size_t)(bxg * NT_TILES) * 128 * D_DIM;
        #pragma unroll
        for (int i = 0; i < 8; ++i) {
            int row = i * 16 + r;
            float4 v0 = ((const float4*)Bsrc)[(size_t)row * 32 + gran * 2];
            float4 v1 = ((const float4*)Bsrc)[(size_t)row * 32 + gran * 2 + 1];
            bf16x8 p = { (bf16_t)v0.x, (bf16_t)v0.y, (bf16_t)v0.z, (bf16_t)v0.w,
                         (bf16_t)v1.x, (bf16_t)v1.y, (bf16_t)v1.z, (bf16_t)v1.w };
            Bls[i * 256 + gran * 16 + (r ^ gran)] = p;
            float s = 0.0f;
            #pragma unroll
            for (int j = 0; j < 8; ++j) { float x = (float)p[j]; s = fmaf(x, x, s); }
            s += __shfl_xor(s, 1); s += __shfl_xor(s, 2);
            s += __shfl_xor(s, 4); s += __shfl_xor(s, 8);
            if (gran == 0) nBs[i * 16 + r] = s;
        }
    }
    lgkm_barrier();

    // ---- A fragments + L norms into registers (Als is dead afterwards)
    const int wM = (wid >> 1) * 64;
    const int wN = (wid & 1) * 64;
    const int agrp = (wid >> 1) * 4;
    const int bgrp = (wid & 1) * 4;

    bf16x8 af[4][4];
    #pragma unroll
    for (int kk = 0; kk < 4; ++kk) {
        int gr = kk * 4 + h;
        int gi = gr * 16 + (lr ^ gr);
        #pragma unroll
        for (int mt = 0; mt < 4; ++mt)
            af[mt][kk] = Als[(agrp + mt) * 256 + gi];
    }
    float l2v[4];
    #pragma unroll
    for (int mt = 0; mt < 4; ++mt) l2v[mt] = nAs[wM + mt * 16 + lr];

    // ---- tile loop
    for (int t = 0; t < NT_TILES; ++t) {
        const int bx = bxg * NT_TILES + t;

        // 1. MFMA on current B tile
        f32x4 acc[4][4] = {};
        #pragma unroll
        for (int kk = 0; kk < 4; ++kk) {
            int gr = kk * 4 + h;
            int gi = gr * 16 + (lr ^ gr);
            bf16x8 bfr[4];
            #pragma unroll
            for (int q = 0; q < 4; ++q)
                bfr[q] = Bls[(bgrp + q) * 256 + gi];
            #pragma unroll
            for (int mt = 0; mt < 4; ++mt)
                #pragma unroll
                for (int q = 0; q < 4; ++q)
                    acc[mt][q] = __builtin_amdgcn_mfma_f32_16x16x32_bf16(
                        bfr[q], af[mt][kk], acc[mt][q], 0, 0, 0);
        }

        // 2. prefetch next B tile (f32) into regs BEFORE any stores issue
        float4 pf0[8], pf1[8];
        if (t + 1 < NT_TILES) {
            const float* Bsrc = Rbat + (size_t)(bx + 1) * 128 * D_DIM;
            #pragma unroll
            for (int i = 0; i < 8; ++i) {
                int row = i * 16 + r;
                pf0[i] = ((const float4*)Bsrc)[(size_t)row * 32 + gran * 2];
                pf1[i] = ((const float4*)Bsrc)[(size_t)row * 32 + gran * 2 + 1];
            }
        }

        // 3. epilogue math (in MFMA layout, in place)
        f32x4 r2v[4];
        #pragma unroll
        for (int q = 0; q < 4; ++q)
            r2v[q] = *(const f32x4*)&nBs[wN + q * 16 + h * 4];
        #pragma unroll
        for (int mt = 0; mt < 4; ++mt) {
            const float l2 = l2v[mt];
            #pragma unroll
            for (int q = 0; q < 4; ++q) {
                #pragma unroll
                for (int e = 0; e < 4; ++e) {
                    float d2 = fmaf(-2.0f, acc[mt][q][e], l2 + r2v[q][e]);
                    d2 = fmaxf(d2, 0.0f);
                    float sq = __builtin_amdgcn_sqrtf(d2);
                    acc[mt][q][e] = __builtin_amdgcn_rcpf(1.0f + sq);
                }
            }
        }

        // 4. all waves done reading Bls (Obuf write clobbers it)
        lgkm_barrier();

        // 5. write finished tile into Obuf (f32x4 granules, swizzled)
        #pragma unroll
        for (int mt = 0; mt < 4; ++mt) {
            const int row = wM + mt * 16 + lr;
            #pragma unroll
            for (int q = 0; q < 4; ++q) {
                const int g = (wN >> 2) + q * 4 + h;     // granule col 0..31
                ldsq[row * 32 + (g ^ (row & 7))] = acc[mt][q];
            }
        }

        // 6. Obuf visible to all waves
        lgkm_barrier();

        // 7. read back row-major, store contiguous 512B row segments
        const size_t outBase =
            ((size_t)bz * N_DIM + (size_t)by * 128) * M_DIM + (size_t)bx * 128;
        {
            const int g = lane & 31;
            #pragma unroll
            for (int i = 0; i < 16; ++i) {
                const int row = wid * 32 + i * 2 + (lane >> 5);
                f32x4 v = ldsq[row * 32 + (g ^ (row & 7))];
                *(f32x4*)(out + outBase + (size_t)row * M_DIM + g * 4) = v;
            }
        }

        // 8. restage next B tile from prefetched regs
        if (t + 1 < NT_TILES) {
            lgkm_barrier();                    // Obuf reads done (Bls region)
            #pragma unroll
            for (int i = 0; i < 8; ++i) {
                bf16x8 p = { (bf16_t)pf0[i].x, (bf16_t)pf0[i].y,
                             (bf16_t)pf0[i].z, (bf16_t)pf0[i].w,
                             (bf16_t)pf1[i].x, (bf16_t)pf1[i].y,
                             (bf16_t)pf1[i].z, (bf16_t)pf1[i].w };
                Bls[i * 256 + gran * 16 + (r ^ gran)] = p;
                float s = 0.0f;
                #pragma unroll
                for (int j = 0; j < 8; ++j) { float x = (float)p[j]; s = fmaf(x, x, s); }
                s += __shfl_xor(s, 1); s += __shfl_xor(s, 2);
                s += __shfl_xor(s, 4); s += __shfl_xor(s, 8);
                if (gran == 0) nBs[i * 16 + r] = s;
            }
            lgkm_barrier();                    // staging visible
        }
    }
}

extern "C" void kernel_launch(void* const* d_in, const int* in_sizes, int n_in,
                              void* d_out, int out_size, void* d_ws, size_t ws_size,
                              hipStream_t stream) {
    const float* L = (const float*)d_in[0];
    const float* R = (const float*)d_in[1];
    float* out = (float*)d_out;

    dim3 grid(M_DIM / (128 * NT_TILES), N_DIM / 128, B_DIM);  // 4 x 16 x 8 = 512
    dim3 block(256);
    fused_dist_kernel<<<grid, block, 0, stream>>>(L, R, out);
}